// Round 6
// baseline (536.549 us; speedup 1.0000x reference)
//
#include <hip/hip_runtime.h>
#include <math.h>

#define T_TOTAL 16384
#define HDIM    2048
#define NEXP    64

// ---------------------------------------------------------------------------
// GEMM:  partial[ks][e][t] = sum_{k in slice ks} x[t][k] * w[e][k]
//
// Block: 256 threads = 4 waves, 256 tokens x 64 experts.
//   wave -> 16 experts (e0 wave-uniform via readfirstlane => W through the
//           SCALAR pipe: s_load_dwordx4, zero VALU/LDS cost)
//   lane -> 4 consecutive tokens (one lane-linear ds_read_b128 per k)
// Accumulators are 16 NAMED float4 (4 tokens x 16 experts) expanded via
// macros -- no dynamically-indexed array, so no scratch spill (the R3/R5
// failure mode). LDS holds only X: 0.25 B/FMA, ~25-37% of LDS pipe at full
// VALU rate (R4 was LDS-BW-bound at 1.0 B/FMA).
// Stores: one b128 per expert, 64 lanes contiguous (1 KB/instr) -- no
// partial-sector write amplification (R5's 283 MB WRITE bug).
// ---------------------------------------------------------------------------
template<int KS>
__global__ __launch_bounds__(256, 4)
void router_gemm_kernel(const float* __restrict__ x,
                        const float* __restrict__ w,
                        float* __restrict__ partial)
{
    constexpr int KSLICE = HDIM / KS;   // 128 for KS=16
    constexpr int BK     = 16;
    constexpr int XS_ST  = 260;         // 256 + 4: 16B-aligned rows, 2-way staging

    __shared__ __align__(16) float Xs[BK][XS_ST];

    const int tid  = threadIdx.x;
    const int lane = tid & 63;
    const int wid  = __builtin_amdgcn_readfirstlane(tid >> 6);  // uniform wave id
    const int tb   = blockIdx.x & 63;    // token block
    const int ks   = blockIdx.x >> 6;    // k-slice
    const int t0   = tb * 256;
    const int k0   = ks * KSLICE;
    const int e0   = wid * 16;           // this wave's 16 experts (uniform)
    const int l4   = lane * 4;           // this lane's 4 tokens

    const int kq = tid & 3;              // X staging k-quad
    const int rr = tid >> 2;             // X staging row 0..63

    const float* wbase = w + (size_t)e0 * HDIM + k0;   // uniform -> s_load

    float4 A0 = {0,0,0,0}, A1 = {0,0,0,0}, A2 = {0,0,0,0}, A3 = {0,0,0,0};
    float4 A4 = {0,0,0,0}, A5 = {0,0,0,0}, A6 = {0,0,0,0}, A7 = {0,0,0,0};
    float4 A8 = {0,0,0,0}, A9 = {0,0,0,0}, A10 = {0,0,0,0}, A11 = {0,0,0,0};
    float4 A12 = {0,0,0,0}, A13 = {0,0,0,0}, A14 = {0,0,0,0}, A15 = {0,0,0,0};

// one expert j over a 4-k group: s_load_dwordx4 of W + 16 fmaf
#define EXPQ(j)                                                             \
    {                                                                       \
        const float4 wv = *(const float4*)(wbase + (size_t)(j) * HDIM + kc + kk); \
        A##j.x = fmaf(xr0.x, wv.x, A##j.x);                                 \
        A##j.y = fmaf(xr0.y, wv.x, A##j.y);                                 \
        A##j.z = fmaf(xr0.z, wv.x, A##j.z);                                 \
        A##j.w = fmaf(xr0.w, wv.x, A##j.w);                                 \
        A##j.x = fmaf(xr1.x, wv.y, A##j.x);                                 \
        A##j.y = fmaf(xr1.y, wv.y, A##j.y);                                 \
        A##j.z = fmaf(xr1.z, wv.y, A##j.z);                                 \
        A##j.w = fmaf(xr1.w, wv.y, A##j.w);                                 \
        A##j.x = fmaf(xr2.x, wv.z, A##j.x);                                 \
        A##j.y = fmaf(xr2.y, wv.z, A##j.y);                                 \
        A##j.z = fmaf(xr2.z, wv.z, A##j.z);                                 \
        A##j.w = fmaf(xr2.w, wv.z, A##j.w);                                 \
        A##j.x = fmaf(xr3.x, wv.w, A##j.x);                                 \
        A##j.y = fmaf(xr3.y, wv.w, A##j.y);                                 \
        A##j.z = fmaf(xr3.z, wv.w, A##j.z);                                 \
        A##j.w = fmaf(xr3.w, wv.w, A##j.w);                                 \
    }

#pragma unroll 1
    for (int kc = 0; kc < KSLICE; kc += BK) {
        __syncthreads();

        // stage X tile: 256 tokens x 16 k, transposed -> [k][token]
        {
            const float* xg = x + (size_t)t0 * HDIM + (k0 + kc) + kq * 4;
#pragma unroll
            for (int p = 0; p < 4; ++p) {
                const int r = p * 64 + rr;
                const float4 v = *(const float4*)(xg + (size_t)r * HDIM);
                Xs[kq * 4 + 0][r] = v.x;
                Xs[kq * 4 + 1][r] = v.y;
                Xs[kq * 4 + 2][r] = v.z;
                Xs[kq * 4 + 3][r] = v.w;
            }
        }
        __syncthreads();

#pragma unroll
        for (int kk = 0; kk < BK; kk += 4) {
            const float4 xr0 = *(const float4*)&Xs[kk + 0][l4];
            const float4 xr1 = *(const float4*)&Xs[kk + 1][l4];
            const float4 xr2 = *(const float4*)&Xs[kk + 2][l4];
            const float4 xr3 = *(const float4*)&Xs[kk + 3][l4];
            EXPQ(0)  EXPQ(1)  EXPQ(2)  EXPQ(3)
            EXPQ(4)  EXPQ(5)  EXPQ(6)  EXPQ(7)
            EXPQ(8)  EXPQ(9)  EXPQ(10) EXPQ(11)
            EXPQ(12) EXPQ(13) EXPQ(14) EXPQ(15)
        }
    }
#undef EXPQ

    // store: partial[ks][e0+j][t0 + 4*lane .. +3] -- one coalesced b128/expert
    float* pb = partial + ((size_t)ks * NEXP + e0) * T_TOTAL + t0 + l4;
#define ST(j) *(float4*)(pb + (size_t)(j) * T_TOTAL) = A##j;
    ST(0)  ST(1)  ST(2)  ST(3)  ST(4)  ST(5)  ST(6)  ST(7)
    ST(8)  ST(9)  ST(10) ST(11) ST(12) ST(13) ST(14) ST(15)
#undef ST
}

// ---------------------------------------------------------------------------
// Thread-per-token: sum KS partials (reads coalesced along t), sigmoid,
// biased top-8 via 8-deep bubble insertion (strict > => ties keep lower
// index, matching lax.top_k), renorm * 2.5.
// ---------------------------------------------------------------------------
__global__ __launch_bounds__(64)
void router_topk_kernel(const float* __restrict__ partial,
                        const float* __restrict__ bias,
                        float* __restrict__ out_scores,
                        float* __restrict__ out_idx,
                        int ksCount)
{
    const int token = blockIdx.x * 64 + threadIdx.x;

    float k8[8], s8[8];
    int   i8[8];
#pragma unroll
    for (int j = 0; j < 8; ++j) { k8[j] = -3.4e38f; s8[j] = 0.0f; i8[j] = 0; }

#pragma unroll 4
    for (int e = 0; e < NEXP; ++e) {
        const float* p = partial + (size_t)e * T_TOTAL + token;
        float lg = 0.0f;
        for (int s = 0; s < ksCount; ++s)
            lg += p[(size_t)s * NEXP * T_TOTAL];

        const float sc = 1.0f / (1.0f + expf(-lg));
        float ck = sc + bias[e];   // bias[e]: uniform -> s_load
        float cs = sc;
        int   ci = e;
#pragma unroll
        for (int j = 0; j < 8; ++j) {
            const bool gt = ck > k8[j];
            const float tk = k8[j], ts = s8[j];
            const int   ti = i8[j];
            if (gt) { k8[j] = ck; s8[j] = cs; i8[j] = ci; ck = tk; cs = ts; ci = ti; }
        }
    }

    float denom = 0.0f;
#pragma unroll
    for (int j = 0; j < 8; ++j) denom += s8[j];
    const float f = 2.5f / (denom + 1e-20f);

#pragma unroll
    for (int j = 0; j < 8; ++j) {
        out_scores[(size_t)token * 8 + j] = s8[j] * f;
        out_idx  [(size_t)token * 8 + j] = (float)i8[j];
    }
}

// ---------------------------------------------------------------------------
extern "C" void kernel_launch(void* const* d_in, const int* in_sizes, int n_in,
                              void* d_out, int out_size, void* d_ws, size_t ws_size,
                              hipStream_t stream)
{
    const float* x    = (const float*)d_in[0];   // [4,4096,2048] f32
    const float* bias = (const float*)d_in[1];   // [64] f32
    const float* w    = (const float*)d_in[2];   // [64,2048] f32

    float* out     = (float*)d_out;
    float* partial = (float*)d_ws;

    const size_t bytesPerSlice = (size_t)T_TOTAL * NEXP * 4;   // 4 MiB

    int ksCount;
    if (ws_size >= 16 * bytesPerSlice) {         // 64 MiB (confirmed available)
        ksCount = 16;
        router_gemm_kernel<16><<<dim3(64 * 16), dim3(256), 0, stream>>>(x, w, partial);
    } else {
        ksCount = 4;
        router_gemm_kernel<4><<<dim3(64 * 4), dim3(256), 0, stream>>>(x, w, partial);
    }

    router_topk_kernel<<<dim3(T_TOTAL / 64), dim3(64), 0, stream>>>(
        partial, bias, out, out + (size_t)T_TOTAL * 8, ksCount);
}

// Round 7
// 354.824 us; speedup vs baseline: 1.5122x; 1.5122x over previous
//
#include <hip/hip_runtime.h>
#include <math.h>

#define T_TOTAL 16384
#define HDIM    2048
#define NEXP    64

// ---------------------------------------------------------------------------
// GEMM:  partial[ks][e][t] = sum_{k in slice ks} x[t][k] * w[e][k]
// (unchanged from round 6 -- dropped out of top-5, i.e. < topk's 269 us)
// Block: 256 threads = 4 waves, 256 tokens x 64 experts.
//   wave -> 16 experts (uniform => W via scalar pipe s_load)
//   lane -> 4 consecutive tokens (lane-linear ds_read_b128)
// 16 named float4 accumulators -> no dynamic indexing -> no scratch spill.
// Stores: one coalesced b128 per expert (1 KB/instr per wave).
// ---------------------------------------------------------------------------
template<int KS>
__global__ __launch_bounds__(256, 4)
void router_gemm_kernel(const float* __restrict__ x,
                        const float* __restrict__ w,
                        float* __restrict__ partial)
{
    constexpr int KSLICE = HDIM / KS;   // 128 for KS=16
    constexpr int BK     = 16;
    constexpr int XS_ST  = 260;         // 16B-aligned rows, 2-way staging = free

    __shared__ __align__(16) float Xs[BK][XS_ST];

    const int tid  = threadIdx.x;
    const int lane = tid & 63;
    const int wid  = __builtin_amdgcn_readfirstlane(tid >> 6);
    const int tb   = blockIdx.x & 63;
    const int ks   = blockIdx.x >> 6;
    const int t0   = tb * 256;
    const int k0   = ks * KSLICE;
    const int e0   = wid * 16;
    const int l4   = lane * 4;

    const int kq = tid & 3;
    const int rr = tid >> 2;

    const float* wbase = w + (size_t)e0 * HDIM + k0;   // uniform -> s_load

    float4 A0 = {0,0,0,0}, A1 = {0,0,0,0}, A2 = {0,0,0,0}, A3 = {0,0,0,0};
    float4 A4 = {0,0,0,0}, A5 = {0,0,0,0}, A6 = {0,0,0,0}, A7 = {0,0,0,0};
    float4 A8 = {0,0,0,0}, A9 = {0,0,0,0}, A10 = {0,0,0,0}, A11 = {0,0,0,0};
    float4 A12 = {0,0,0,0}, A13 = {0,0,0,0}, A14 = {0,0,0,0}, A15 = {0,0,0,0};

#define EXPQ(j)                                                             \
    {                                                                       \
        const float4 wv = *(const float4*)(wbase + (size_t)(j) * HDIM + kc + kk); \
        A##j.x = fmaf(xr0.x, wv.x, A##j.x);                                 \
        A##j.y = fmaf(xr0.y, wv.x, A##j.y);                                 \
        A##j.z = fmaf(xr0.z, wv.x, A##j.z);                                 \
        A##j.w = fmaf(xr0.w, wv.x, A##j.w);                                 \
        A##j.x = fmaf(xr1.x, wv.y, A##j.x);                                 \
        A##j.y = fmaf(xr1.y, wv.y, A##j.y);                                 \
        A##j.z = fmaf(xr1.z, wv.y, A##j.z);                                 \
        A##j.w = fmaf(xr1.w, wv.y, A##j.w);                                 \
        A##j.x = fmaf(xr2.x, wv.z, A##j.x);                                 \
        A##j.y = fmaf(xr2.y, wv.z, A##j.y);                                 \
        A##j.z = fmaf(xr2.z, wv.z, A##j.z);                                 \
        A##j.w = fmaf(xr2.w, wv.z, A##j.w);                                 \
        A##j.x = fmaf(xr3.x, wv.w, A##j.x);                                 \
        A##j.y = fmaf(xr3.y, wv.w, A##j.y);                                 \
        A##j.z = fmaf(xr3.z, wv.w, A##j.z);                                 \
        A##j.w = fmaf(xr3.w, wv.w, A##j.w);                                 \
    }

#pragma unroll 1
    for (int kc = 0; kc < KSLICE; kc += BK) {
        __syncthreads();
        {
            const float* xg = x + (size_t)t0 * HDIM + (k0 + kc) + kq * 4;
#pragma unroll
            for (int p = 0; p < 4; ++p) {
                const int r = p * 64 + rr;
                const float4 v = *(const float4*)(xg + (size_t)r * HDIM);
                Xs[kq * 4 + 0][r] = v.x;
                Xs[kq * 4 + 1][r] = v.y;
                Xs[kq * 4 + 2][r] = v.z;
                Xs[kq * 4 + 3][r] = v.w;
            }
        }
        __syncthreads();

#pragma unroll
        for (int kk = 0; kk < BK; kk += 4) {
            const float4 xr0 = *(const float4*)&Xs[kk + 0][l4];
            const float4 xr1 = *(const float4*)&Xs[kk + 1][l4];
            const float4 xr2 = *(const float4*)&Xs[kk + 2][l4];
            const float4 xr3 = *(const float4*)&Xs[kk + 3][l4];
            EXPQ(0)  EXPQ(1)  EXPQ(2)  EXPQ(3)
            EXPQ(4)  EXPQ(5)  EXPQ(6)  EXPQ(7)
            EXPQ(8)  EXPQ(9)  EXPQ(10) EXPQ(11)
            EXPQ(12) EXPQ(13) EXPQ(14) EXPQ(15)
        }
    }
#undef EXPQ

    float* pb = partial + ((size_t)ks * NEXP + e0) * T_TOTAL + t0 + l4;
#define ST(j) *(float4*)(pb + (size_t)(j) * T_TOTAL) = A##j;
    ST(0)  ST(1)  ST(2)  ST(3)  ST(4)  ST(5)  ST(6)  ST(7)
    ST(8)  ST(9)  ST(10) ST(11) ST(12) ST(13) ST(14) ST(15)
#undef ST
}

// ---------------------------------------------------------------------------
// Fused reduce + sigmoid + top-8.  Block = 256 threads / 64 tokens.
// Phase 1: (wave,lane) = (expert-subset, token) -> coalesced 256 B reads,
//          KS loads fully unrolled & independent; scores into LDS [t][e]
//          (stride 65 -> 2-way bank alias = free).
// Phase 2: wave-per-token (16 tokens/wave) shuffle argmax top-8 with
//          lower-index tie-break (matches lax.top_k), renorm * 2.5.
// Grid 256 blocks x 4 waves = 4 blocks/CU (vs 1 wave/CU in round 6).
// ---------------------------------------------------------------------------
template<int KS>
__global__ __launch_bounds__(256)
void router_topk_kernel(const float* __restrict__ partial,
                        const float* __restrict__ bias,
                        float* __restrict__ out_scores,
                        float* __restrict__ out_idx)
{
    __shared__ float Ls[64][65];

    const int tid  = threadIdx.x;
    const int lane = tid & 63;
    const int wv   = tid >> 6;
    const int t0   = blockIdx.x * 64;

    // Phase 1: logits -> sigmoid -> LDS
#pragma unroll
    for (int it = 0; it < 16; ++it) {
        const int e = it * 4 + wv;
        const float* p = partial + (size_t)e * T_TOTAL + t0 + lane;
        float lg = 0.0f;
#pragma unroll
        for (int s = 0; s < KS; ++s)
            lg += p[(size_t)s * NEXP * T_TOTAL];
        Ls[lane][e] = 1.0f / (1.0f + expf(-lg));
    }
    __syncthreads();

    const float bv = bias[lane];

    // Phase 2: top-8 per token, 16 tokens per wave
#pragma unroll 1
    for (int tt = 0; tt < 16; ++tt) {
        const int trow  = wv * 16 + tt;
        const int token = t0 + trow;
        const float score = Ls[trow][lane];
        float key = score + bv;

        float myscore = 0.0f;
        int   myidx   = 0;
        float denom   = 0.0f;
#pragma unroll
        for (int r = 0; r < 8; ++r) {
            float bk = key;
            int   bi = lane;
#pragma unroll
            for (int off = 32; off > 0; off >>= 1) {
                const float ok = __shfl_xor(bk, off);
                const int   oi = __shfl_xor(bi, off);
                if (ok > bk || (ok == bk && oi < bi)) { bk = ok; bi = oi; }
            }
            const float wsc = __shfl(score, bi);
            denom += wsc;
            if (lane == r)  { myscore = wsc; myidx = bi; }
            if (lane == bi) key = -__builtin_inff();
        }
        const float f = 2.5f / (denom + 1e-20f);
        if (lane < 8) {
            out_scores[(size_t)token * 8 + lane] = myscore * f;
            out_idx  [(size_t)token * 8 + lane] = (float)myidx;
        }
    }
}

// ---------------------------------------------------------------------------
extern "C" void kernel_launch(void* const* d_in, const int* in_sizes, int n_in,
                              void* d_out, int out_size, void* d_ws, size_t ws_size,
                              hipStream_t stream)
{
    const float* x    = (const float*)d_in[0];   // [4,4096,2048] f32
    const float* bias = (const float*)d_in[1];   // [64] f32
    const float* w    = (const float*)d_in[2];   // [64,2048] f32

    float* out     = (float*)d_out;
    float* partial = (float*)d_ws;

    const size_t bytesPerSlice = (size_t)T_TOTAL * NEXP * 4;   // 4 MiB

    if (ws_size >= 16 * bytesPerSlice) {
        router_gemm_kernel<16><<<dim3(64 * 16), dim3(256), 0, stream>>>(x, w, partial);
        router_topk_kernel<16><<<dim3(T_TOTAL / 64), dim3(256), 0, stream>>>(
            partial, bias, out, out + (size_t)T_TOTAL * 8);
    } else {
        router_gemm_kernel<4><<<dim3(64 * 4), dim3(256), 0, stream>>>(x, w, partial);
        router_topk_kernel<4><<<dim3(T_TOTAL / 64), dim3(256), 0, stream>>>(
            partial, bias, out, out + (size_t)T_TOTAL * 8);
    }
}